// Round 7
// baseline (278.572 us; speedup 1.0000x reference)
//
#include <hip/hip_runtime.h>
#include <hip/hip_bf16.h>

typedef unsigned long long ull;

#define B_ROWS 32768
#define D_COLS 2048
#define K_SEL  40
#define T_LO   1.74f          // P(x>1.74)=0.0409 -> C ~ 84 +- 9, in [40,128] at ~4.9 sigma
#define CAP    128            // candidate capacity (2 select-slots per lane of wave 0)
#define ALPHA_F  0.01f
#define TARGET_F 0.01953125f  // 40/2048 exact
#define G_COPIES 16           // histogram copies; multiple of 8 => XCD-local atomics

__device__ __forceinline__ ull fkey(float vv, unsigned col) {
    // monotone (value desc via max, index asc via ~col) 64-bit key
    unsigned bits = __float_as_uint(vv);
    unsigned sk = (bits & 0x80000000u) ? ~bits : (bits | 0x80000000u);
    return ((ull)sk << 32) | (ull)(unsigned)(~col);
}

__device__ __forceinline__ float f4elem(const float4& q, int j) {
    return j == 0 ? q.x : j == 1 ? q.y : j == 2 ? q.z : q.w;
}

// Kernel 0: zero the privatized histograms (rocclr fillBuffer launches a tiny
// grid for small buffers; DIY at full BW).
__global__ __launch_bounds__(256) void kwta_zero_kernel(uint4* __restrict__ p) {
    p[blockIdx.x * 256 + threadIdx.x] = make_uint4(0u, 0u, 0u, 0u);
}

// Kernel 1: per-row exact top-K, one BLOCK (4 waves) per row. 8 elems/lane:
// short predicate/compaction chains, low VGPR, 32768 blocks for latency
// hiding. Waves 1-3 only load+compact; wave 0 runs the exact radix select
// over the <=128 candidates and emits 40 (val,col) pairs into the row's
// out-slice header (scratch; kernel 3 overwrites the row) + histogram counts.
__global__ __launch_bounds__(256) void kwta_topk_kernel(
        const float* __restrict__ x, float* __restrict__ out,
        unsigned* __restrict__ cnt) {
    __shared__ float2 cands[CAP];
    __shared__ unsigned wcnt[4];

    const int lane = threadIdx.x & 63;
    const int wid  = threadIdx.x >> 6;
    const int row  = blockIdx.x;
    const float* xr = x + (size_t)row * D_COLS;
    const ull lm_lt = (1ull << lane) - 1ull;
    float* hdr = out + (size_t)row * D_COLS;
    unsigned* mycnt_arr = cnt + ((size_t)(blockIdx.x & (G_COPIES - 1)) << 11);

    // ---- load 8 elements/lane: two coalesced float4 chunks per wave ----
    const int c0 = wid * 512 + lane * 4;        // cols c0..c0+3
    const int c1 = wid * 512 + 256 + lane * 4;  // cols c1..c1+3
    float4 v0 = *reinterpret_cast<const float4*>(xr + c0);
    float4 v1 = *reinterpret_cast<const float4*>(xr + c1);

    // ---- per-lane candidate predicate (8 independent compares) ----
    unsigned m = 0;
#pragma unroll
    for (int j = 0; j < 4; ++j) m |= (f4elem(v0, j) > T_LO ? 1u : 0u) << j;
#pragma unroll
    for (int j = 0; j < 4; ++j) m |= (f4elem(v1, j) > T_LO ? 1u : 0u) << (4 + j);
    const unsigned mycnt = __popc(m);

    // ---- wave-wide inclusive scan (6 shfl steps) ----
    unsigned inc = mycnt;
#pragma unroll
    for (int d = 1; d < 64; d <<= 1) {
        unsigned u = __shfl_up(inc, d, 64);
        if (lane >= d) inc += u;
    }
    if (lane == 63) wcnt[wid] = inc;
    __syncthreads();

    const unsigned t0 = wcnt[0], t1 = wcnt[1], t2 = wcnt[2], t3 = wcnt[3];
    const unsigned C = t0 + t1 + t2 + t3;
    unsigned pos = (wid > 0 ? t0 : 0u) + (wid > 1 ? t1 : 0u) + (wid > 2 ? t2 : 0u)
                 + inc - mycnt;

    // ---- predicated LDS compaction (8-iteration loop) ----
#pragma unroll
    for (int j = 0; j < 8; ++j) {
        if ((m >> j) & 1u) {
            float val    = (j < 4) ? f4elem(v0, j) : f4elem(v1, j - 4);
            unsigned col = (unsigned)((j < 4) ? (c0 + j) : (c1 + j - 4));
            if (pos < CAP) cands[pos] = make_float2(val, __uint_as_float(col));
            ++pos;
        }
    }
    __syncthreads();

    if (wid != 0) return;   // waves 1-3 done (no barriers below)

    if (C >= K_SEL && C <= CAP) {
        // ---- primary: early-exit bitwise radix select, 2 slots/lane ----
        float2 cd0 = cands[lane];
        float2 cd1 = cands[64 + lane];
        const bool ok0 = (unsigned)lane < C;
        const bool ok1 = (unsigned)(64 + lane) < C;
        const float    cv0 = ok0 ? cd0.x : 0.0f;
        const float    cv1 = ok1 ? cd1.x : 0.0f;
        const unsigned kb0 = __float_as_uint(cv0);  // >1.74 => positive => raw-bit order
        const unsigned kb1 = __float_as_uint(cv1);
        const unsigned cc0 = __float_as_uint(cd0.y);
        const unsigned cc1 = __float_as_uint(cd1.y);

        ull a0 = (C >= 64) ? ~0ull : ((1ull << C) - 1ull);
        ull a1 = (C <= 64) ? 0ull : ((C >= 128) ? ~0ull : ((1ull << (C - 64)) - 1ull));
        ull s0 = 0, s1 = 0;
        unsigned kk = K_SEL, na = C;

        if (na == kk) { s0 = a0; s1 = a1; kk = 0; }
        for (int b = 30; b >= 0 && kk; --b) {
            unsigned bit = 1u << b;
            ull b0 = __ballot((kb0 & bit) != 0) & a0;
            ull b1 = __ballot((kb1 & bit) != 0) & a1;
            unsigned cv = (unsigned)__popcll(b0) + (unsigned)__popcll(b1);
            if (cv >= kk) { a0 = b0; a1 = b1; na = cv; }
            else          { s0 |= b0; s1 |= b1; kk -= cv; a0 &= ~b0; a1 &= ~b1; na -= cv; }
            if (na == kk) { s0 |= a0; s1 |= a1; kk = 0; }
        }
        if (kk) {
            // bits exhausted: alive are exactly-equal values; take kk smallest cols
            ull e0 = a0, e1 = a1;
            for (unsigned t = 0; t < kk; ++t) {
                unsigned mymin = 0xFFFFFFFFu;
                if ((e0 >> lane) & 1ull) mymin = min(mymin, cc0);
                if ((e1 >> lane) & 1ull) mymin = min(mymin, cc1);
#pragma unroll
                for (int off = 32; off >= 1; off >>= 1)
                    mymin = min(mymin, (unsigned)__shfl_xor((int)mymin, off, 64));
                bool h0 = ((e0 >> lane) & 1ull) && cc0 == mymin;
                bool h1 = ((e1 >> lane) & 1ull) && cc1 == mymin;
                ull hb0 = __ballot(h0) & e0;
                ull hb1 = __ballot(h1) & e1;
                if (hb0) { s0 |= hb0 & (~hb0 + 1); e0 &= ~(hb0 & (~hb0 + 1)); }
                else     { s1 |= hb1 & (~hb1 + 1); e1 &= ~(hb1 & (~hb1 + 1)); }
            }
        }

        // ---- emit 40 pairs + column counts (XCD-local histogram copy) ----
        unsigned n0 = (unsigned)__popcll(s0);
        if ((s0 >> lane) & 1ull) {
            unsigned p = (unsigned)__popcll(s0 & lm_lt);
            reinterpret_cast<float2*>(hdr)[p] = make_float2(cv0, __uint_as_float(cc0));
            atomicAdd(&mycnt_arr[cc0], 1u);
        }
        if ((s1 >> lane) & 1ull) {
            unsigned p = n0 + (unsigned)__popcll(s1 & lm_lt);
            reinterpret_cast<float2*>(hdr)[p] = make_float2(cv1, __uint_as_float(cc1));
            atomicAdd(&mycnt_arr[cc1], 1u);
        }
    } else {
        // ---- fully general fallback (statistically never for N(0,1) data):
        //      wave 0 does K exact argmax rounds over the row (L2-hot reloads)
        unsigned rm = 0;
        for (int t = 0; t < K_SEL; ++t) {
            ull best = 0;
#pragma unroll
            for (int s = 0; s < 8; ++s) {
                float4 q = *reinterpret_cast<const float4*>(xr + s * 256 + lane * 4);
#pragma unroll
                for (int j = 0; j < 4; ++j) {
                    int slot = s * 4 + j;
                    if (!((rm >> slot) & 1u)) {
                        ull key = fkey(f4elem(q, j), (unsigned)(s * 256 + lane * 4 + j));
                        best = best > key ? best : key;
                    }
                }
            }
#pragma unroll
            for (int off = 32; off >= 1; off >>= 1) {
                ull o = __shfl_xor(best, off, 64);
                best = best > o ? best : o;
            }
#pragma unroll
            for (int s = 0; s < 8; ++s) {
                float4 q = *reinterpret_cast<const float4*>(xr + s * 256 + lane * 4);
#pragma unroll
                for (int j = 0; j < 4; ++j) {
                    int slot = s * 4 + j;
                    unsigned col = (unsigned)(s * 256 + lane * 4 + j);
                    if (!((rm >> slot) & 1u) && fkey(f4elem(q, j), col) == best) {
                        rm |= 1u << slot;
                        reinterpret_cast<float2*>(hdr)[t] =
                            make_float2(f4elem(q, j), __uint_as_float(col));
                        atomicAdd(&mycnt_arr[col], 1u);
                    }
                }
            }
        }
    }
}

// Kernel 2: sum 16 histogram copies; boost[d] = exp(-(duty*0.99 + 0.01*cnt/B
// - target)). 16 blocks x 128 threads: readers spread over all XCDs.
__global__ __launch_bounds__(128) void kwta_boost_kernel(
        const float* __restrict__ duty, const unsigned* __restrict__ cnt,
        float* __restrict__ boost) {
    int d = blockIdx.x * 128 + threadIdx.x;
    unsigned s = 0;
#pragma unroll
    for (int g = 0; g < G_COPIES; ++g) s += cnt[((size_t)g << 11) + d];
    float mean = (float)s * (1.0f / 32768.0f);
    float nd = duty[d] * (1.0f - ALPHA_F) + ALPHA_F * mean;
    boost[d] = expf(-(nd - TARGET_F));
}

// Kernel 3: block-per-row; read 40 pairs from row header, build row in LDS,
// write fully-coalesced float4s (overwrites header with the real output).
__global__ __launch_bounds__(256) void kwta_scatter_kernel(
        float* __restrict__ out, const float* __restrict__ boost) {
    __shared__ float buf[D_COLS];
    const int t = threadIdx.x;
    const size_t rb = (size_t)blockIdx.x * D_COLS;

    float2 pr = make_float2(0.0f, 0.0f);
    if (t < K_SEL) pr = reinterpret_cast<const float2*>(out + rb)[t];

    float4 z = make_float4(0.0f, 0.0f, 0.0f, 0.0f);
    reinterpret_cast<float4*>(buf)[t * 2]     = z;
    reinterpret_cast<float4*>(buf)[t * 2 + 1] = z;
    __syncthreads();

    if (t < K_SEL) {
        unsigned col = __float_as_uint(pr.y);
        buf[col] = pr.x * boost[col];
    }
    __syncthreads();

    reinterpret_cast<float4*>(out + rb)[t * 2]     = reinterpret_cast<const float4*>(buf)[t * 2];
    reinterpret_cast<float4*>(out + rb)[t * 2 + 1] = reinterpret_cast<const float4*>(buf)[t * 2 + 1];
}

extern "C" void kernel_launch(void* const* d_in, const int* in_sizes, int n_in,
                              void* d_out, int out_size, void* d_ws, size_t ws_size,
                              hipStream_t stream) {
    const float* x    = (const float*)d_in[0];
    const float* duty = (const float*)d_in[1];
    float* out = (float*)d_out;

    unsigned* cnt   = (unsigned*)d_ws;                                 // 16 * 8 KB
    float*    boost = (float*)((char*)d_ws + (size_t)G_COPIES * 8192); // 8 KB

    // zero 16*8KB = 128KB of histograms: 32 blocks x 256 threads x 16B
    kwta_zero_kernel<<<G_COPIES * 8192 / 4096, 256, 0, stream>>>((uint4*)d_ws);

    kwta_topk_kernel<<<B_ROWS, 256, 0, stream>>>(x, out, cnt);
    kwta_boost_kernel<<<D_COLS / 128, 128, 0, stream>>>(duty, cnt, boost);
    kwta_scatter_kernel<<<B_ROWS, 256, 0, stream>>>(out, boost);
}

// Round 8
// 157.558 us; speedup vs baseline: 1.7681x; 1.7681x over previous
//
#include <hip/hip_runtime.h>
#include <hip/hip_bf16.h>

typedef unsigned long long ull;

#define B_ROWS 32768
#define D_COLS 2048
#define K_SEL  40
#define T_LO   1.74f          // P(x>1.74)=0.0409 -> C ~ 84 +- 9, in [40,128] at ~4.9 sigma
#define CAP    128            // 2 select-slots per lane
#define ALPHA_F  0.01f
#define TARGET_F 0.01953125f  // 40/2048 exact
#define G_COPIES 16           // histogram copies; multiple of 8 => XCD-local atomics

__device__ __forceinline__ ull fkey(float vv, unsigned col) {
    // monotone (value desc via max, index asc via ~col) 64-bit key
    unsigned bits = __float_as_uint(vv);
    unsigned sk = (bits & 0x80000000u) ? ~bits : (bits | 0x80000000u);
    return ((ull)sk << 32) | (ull)(unsigned)(~col);
}

__device__ __forceinline__ float f4elem(const float4& q, int j) {
    return j == 0 ? q.x : j == 1 ? q.y : j == 2 ? q.z : q.w;
}

// Kernel 0: zero the privatized histograms (rocclr fillBuffer launches a tiny
// grid for small buffers; DIY at full BW).
__global__ __launch_bounds__(256) void kwta_zero_kernel(uint4* __restrict__ p) {
    p[blockIdx.x * 256 + threadIdx.x] = make_uint4(0u, 0u, 0u, 0u);
}

// Kernel 1: per-row exact top-K, one WAVE per row (R6 structure — best
// measured). Serial-chain cuts vs R6:
//  (a) bit-plane ballot scan (6 independent ballots) replaces the 6-step
//      dependent __shfl_up scan (~700 cyc of ds_bpermute latency);
//  (b) branchless compaction: unconditional ds_write to (pred ? pos :
//      per-lane trash slot) — no exec-mask churn, no per-element branch.
__global__ __launch_bounds__(256, 3) void kwta_topk_kernel(
        const float* __restrict__ x, float* __restrict__ out,
        unsigned* __restrict__ cnt) {
    __shared__ float2 cands[4][CAP + 64];   // +64 per-lane trash slots

    const int lane = threadIdx.x & 63;
    const int wid  = threadIdx.x >> 6;
    const int row  = blockIdx.x * 4 + wid;
    const float* xr = x + (size_t)row * D_COLS;
    const ull lm_lt = (1ull << lane) - 1ull;
    float2* my = cands[wid];
    float* hdr = out + (size_t)row * D_COLS;
    unsigned* mycnt_arr = cnt + ((size_t)(blockIdx.x & (G_COPIES - 1)) << 11);

    // ---- load 32 elements/lane, coalesced (8 independent dwordx4) ----
    float4 v[8];
#pragma unroll
    for (int s = 0; s < 8; ++s)
        v[s] = *reinterpret_cast<const float4*>(xr + s * 256 + lane * 4);

    // ---- per-lane candidate predicate mask (32 independent compares) ----
    unsigned m = 0;
#pragma unroll
    for (int s = 0; s < 8; ++s) {
#pragma unroll
        for (int j = 0; j < 4; ++j)
            m |= (f4elem(v[s], j) > T_LO ? 1u : 0u) << (s * 4 + j);
    }
    const unsigned mycnt = __popc(m);

    // ---- bit-plane ballot scan: base (exclusive prefix) and total C.
    //      mycnt in [0,32] -> 6 bits; all 6 ballots independent. ----
    unsigned base = 0, C = 0;
#pragma unroll
    for (int b = 0; b < 6; ++b) {
        ull bal = __ballot(((mycnt >> b) & 1u) != 0u);
        base += ((unsigned)__popcll(bal & lm_lt)) << b;
        C    += ((unsigned)__popcll(bal)) << b;
    }

    // ---- branchless LDS compaction: unconditional write each element to
    //      (pred ? pos : trash). Clamp keeps LDS in-bounds when C > CAP
    //      (fallback path ignores cands then). ----
    {
        unsigned pos = base;
        const unsigned trash = CAP + (unsigned)lane;
#pragma unroll
        for (int s = 0; s < 8; ++s) {
#pragma unroll
            for (int j = 0; j < 4; ++j) {
                unsigned pred = (m >> (s * 4 + j)) & 1u;
                unsigned dst = pred ? pos : trash;
                dst = min(dst, (unsigned)(CAP + 63));
                my[dst] = make_float2(f4elem(v[s], j),
                                      __uint_as_float((unsigned)(s * 256 + lane * 4 + j)));
                pos += pred;
            }
        }
    }

    if (C >= K_SEL && C <= CAP) {
        // ---- primary: early-exit bitwise radix select, 2 slots/lane ----
        float2 cd0 = my[lane];
        float2 cd1 = my[64 + lane];
        const bool ok0 = (unsigned)lane < C;
        const bool ok1 = (unsigned)(64 + lane) < C;
        const float    cv0 = ok0 ? cd0.x : 0.0f;
        const float    cv1 = ok1 ? cd1.x : 0.0f;
        const unsigned kb0 = __float_as_uint(cv0);  // >1.74 => positive => raw-bit order
        const unsigned kb1 = __float_as_uint(cv1);
        const unsigned cc0 = __float_as_uint(cd0.y);
        const unsigned cc1 = __float_as_uint(cd1.y);

        ull a0 = (C >= 64) ? ~0ull : ((1ull << C) - 1ull);
        ull a1 = (C <= 64) ? 0ull : ((C >= 128) ? ~0ull : ((1ull << (C - 64)) - 1ull));
        ull s0 = 0, s1 = 0;
        unsigned kk = K_SEL, na = C;

        if (na == kk) { s0 = a0; s1 = a1; kk = 0; }
        for (int b = 30; b >= 0 && kk; --b) {
            unsigned bit = 1u << b;
            ull b0 = __ballot((kb0 & bit) != 0) & a0;
            ull b1 = __ballot((kb1 & bit) != 0) & a1;
            unsigned cv = (unsigned)__popcll(b0) + (unsigned)__popcll(b1);
            if (cv >= kk) { a0 = b0; a1 = b1; na = cv; }
            else          { s0 |= b0; s1 |= b1; kk -= cv; a0 &= ~b0; a1 &= ~b1; na -= cv; }
            if (na == kk) { s0 |= a0; s1 |= a1; kk = 0; }
        }
        if (kk) {
            // bits exhausted: alive are exactly-equal values; take kk smallest cols
            ull e0 = a0, e1 = a1;
            for (unsigned t = 0; t < kk; ++t) {
                unsigned mymin = 0xFFFFFFFFu;
                if ((e0 >> lane) & 1ull) mymin = min(mymin, cc0);
                if ((e1 >> lane) & 1ull) mymin = min(mymin, cc1);
#pragma unroll
                for (int off = 32; off >= 1; off >>= 1)
                    mymin = min(mymin, (unsigned)__shfl_xor((int)mymin, off, 64));
                bool h0 = ((e0 >> lane) & 1ull) && cc0 == mymin;
                bool h1 = ((e1 >> lane) & 1ull) && cc1 == mymin;
                ull hb0 = __ballot(h0) & e0;
                ull hb1 = __ballot(h1) & e1;
                if (hb0) { s0 |= hb0 & (~hb0 + 1); e0 &= ~(hb0 & (~hb0 + 1)); }
                else     { s1 |= hb1 & (~hb1 + 1); e1 &= ~(hb1 & (~hb1 + 1)); }
            }
        }

        // ---- emit 40 pairs + column counts (XCD-local histogram copy) ----
        unsigned n0 = (unsigned)__popcll(s0);
        if ((s0 >> lane) & 1ull) {
            unsigned p = (unsigned)__popcll(s0 & lm_lt);
            reinterpret_cast<float2*>(hdr)[p] = make_float2(cv0, __uint_as_float(cc0));
            atomicAdd(&mycnt_arr[cc0], 1u);
        }
        if ((s1 >> lane) & 1ull) {
            unsigned p = n0 + (unsigned)__popcll(s1 & lm_lt);
            reinterpret_cast<float2*>(hdr)[p] = make_float2(cv1, __uint_as_float(cc1));
            atomicAdd(&mycnt_arr[cc1], 1u);
        }
    } else {
        // ---- fully general fallback (statistically never for N(0,1) data):
        //      K exact wave-argmax rounds, reloading from global (L2-hot)
        unsigned rm = 0;
        for (int t = 0; t < K_SEL; ++t) {
            ull best = 0;
#pragma unroll
            for (int s = 0; s < 8; ++s) {
                float4 q = *reinterpret_cast<const float4*>(xr + s * 256 + lane * 4);
#pragma unroll
                for (int j = 0; j < 4; ++j) {
                    int slot = s * 4 + j;
                    if (!((rm >> slot) & 1u)) {
                        ull key = fkey(f4elem(q, j), (unsigned)(s * 256 + lane * 4 + j));
                        best = best > key ? best : key;
                    }
                }
            }
#pragma unroll
            for (int off = 32; off >= 1; off >>= 1) {
                ull o = __shfl_xor(best, off, 64);
                best = best > o ? best : o;
            }
#pragma unroll
            for (int s = 0; s < 8; ++s) {
                float4 q = *reinterpret_cast<const float4*>(xr + s * 256 + lane * 4);
#pragma unroll
                for (int j = 0; j < 4; ++j) {
                    int slot = s * 4 + j;
                    unsigned col = (unsigned)(s * 256 + lane * 4 + j);
                    if (!((rm >> slot) & 1u) && fkey(f4elem(q, j), col) == best) {
                        rm |= 1u << slot;
                        reinterpret_cast<float2*>(hdr)[t] =
                            make_float2(f4elem(q, j), __uint_as_float(col));
                        atomicAdd(&mycnt_arr[col], 1u);
                    }
                }
            }
        }
    }
}

// Kernel 2: sum 16 histogram copies; boost[d] = exp(-(duty*0.99 + 0.01*cnt/B
// - target)). 16 blocks x 128 threads: readers spread over all XCDs.
__global__ __launch_bounds__(128) void kwta_boost_kernel(
        const float* __restrict__ duty, const unsigned* __restrict__ cnt,
        float* __restrict__ boost) {
    int d = blockIdx.x * 128 + threadIdx.x;
    unsigned s = 0;
#pragma unroll
    for (int g = 0; g < G_COPIES; ++g) s += cnt[((size_t)g << 11) + d];
    float mean = (float)s * (1.0f / 32768.0f);
    float nd = duty[d] * (1.0f - ALPHA_F) + ALPHA_F * mean;
    boost[d] = expf(-(nd - TARGET_F));
}

// Kernel 3: block-per-row; read 40 pairs from row header, build row in LDS,
// write fully-coalesced float4s (overwrites header with the real output).
__global__ __launch_bounds__(256) void kwta_scatter_kernel(
        float* __restrict__ out, const float* __restrict__ boost) {
    __shared__ float buf[D_COLS];
    const int t = threadIdx.x;
    const size_t rb = (size_t)blockIdx.x * D_COLS;

    float2 pr = make_float2(0.0f, 0.0f);
    if (t < K_SEL) pr = reinterpret_cast<const float2*>(out + rb)[t];

    float4 z = make_float4(0.0f, 0.0f, 0.0f, 0.0f);
    reinterpret_cast<float4*>(buf)[t * 2]     = z;
    reinterpret_cast<float4*>(buf)[t * 2 + 1] = z;
    __syncthreads();

    if (t < K_SEL) {
        unsigned col = __float_as_uint(pr.y);
        buf[col] = pr.x * boost[col];
    }
    __syncthreads();

    reinterpret_cast<float4*>(out + rb)[t * 2]     = reinterpret_cast<const float4*>(buf)[t * 2];
    reinterpret_cast<float4*>(out + rb)[t * 2 + 1] = reinterpret_cast<const float4*>(buf)[t * 2 + 1];
}

extern "C" void kernel_launch(void* const* d_in, const int* in_sizes, int n_in,
                              void* d_out, int out_size, void* d_ws, size_t ws_size,
                              hipStream_t stream) {
    const float* x    = (const float*)d_in[0];
    const float* duty = (const float*)d_in[1];
    float* out = (float*)d_out;

    unsigned* cnt   = (unsigned*)d_ws;                                 // 16 * 8 KB
    float*    boost = (float*)((char*)d_ws + (size_t)G_COPIES * 8192); // 8 KB

    // zero 16*8KB = 128KB of histograms: 32 blocks x 256 threads x 16B
    kwta_zero_kernel<<<G_COPIES * 8192 / 4096, 256, 0, stream>>>((uint4*)d_ws);

    kwta_topk_kernel<<<B_ROWS / 4, 256, 0, stream>>>(x, out, cnt);
    kwta_boost_kernel<<<D_COLS / 128, 128, 0, stream>>>(duty, cnt, boost);
    kwta_scatter_kernel<<<B_ROWS, 256, 0, stream>>>(out, boost);
}

// Round 9
// 154.646 us; speedup vs baseline: 1.8014x; 1.0188x over previous
//
#include <hip/hip_runtime.h>
#include <hip/hip_bf16.h>

typedef unsigned long long ull;

#define B_ROWS 32768
#define D_COLS 2048
#define K_SEL  40
#define T_LO   1.74f          // P(x>1.74)=0.0409 -> C ~ 84 +- 9, in [40,128] at ~4.9 sigma
#define CAP    128            // 2 select-slots per lane
#define ALPHA_F  0.01f
#define TARGET_F 0.01953125f  // 40/2048 exact
#define G_COPIES 16           // histogram copies; multiple of 8 => XCD-local atomics

__device__ __forceinline__ ull fkey(float vv, unsigned col) {
    // monotone (value desc via max, index asc via ~col) 64-bit key
    unsigned bits = __float_as_uint(vv);
    unsigned sk = (bits & 0x80000000u) ? ~bits : (bits | 0x80000000u);
    return ((ull)sk << 32) | (ull)(unsigned)(~col);
}

__device__ __forceinline__ float f4elem(const float4& q, int j) {
    return j == 0 ? q.x : j == 1 ? q.y : j == 2 ? q.z : q.w;
}

// Kernel 0: zero the privatized histograms (rocclr fillBuffer launches a tiny
// grid for small buffers; DIY at full BW).
__global__ __launch_bounds__(256) void kwta_zero_kernel(uint4* __restrict__ p) {
    p[blockIdx.x * 256 + threadIdx.x] = make_uint4(0u, 0u, 0u, 0u);
}

// Kernel 1: per-row exact top-K, one WAVE per row. R9: row processed in TWO
// 16-element halves so only 4 float4s are live at once -> VGPR <= ~56 ->
// 8 blocks/CU (32 waves/CU) for latency hiding. No forced min-waves (R2's
// (256,8) made the compiler clamp to 32 VGPR and spill the row cache).
__global__ __launch_bounds__(256) void kwta_topk_kernel(
        const float* __restrict__ x, float* __restrict__ out,
        unsigned* __restrict__ cnt) {
    __shared__ float2 cands[4][CAP + 64];   // +64 per-lane trash slots

    const int lane = threadIdx.x & 63;
    const int wid  = threadIdx.x >> 6;
    const int row  = blockIdx.x * 4 + wid;
    const float* xr = x + (size_t)row * D_COLS;
    const ull lm_lt = (1ull << lane) - 1ull;
    float2* my = cands[wid];
    float* hdr = out + (size_t)row * D_COLS;
    unsigned* mycnt_arr = cnt + ((size_t)(blockIdx.x & (G_COPIES - 1)) << 11);

    unsigned C = 0;   // running candidate count

    // ---- two halves of 16 elements/lane each ----
#pragma unroll
    for (int h = 0; h < 2; ++h) {
        const int sbase = h * 4;
        // load 4 coalesced float4s (16 VGPRs live)
        float4 v0 = *reinterpret_cast<const float4*>(xr + (sbase + 0) * 256 + lane * 4);
        float4 v1 = *reinterpret_cast<const float4*>(xr + (sbase + 1) * 256 + lane * 4);
        float4 v2 = *reinterpret_cast<const float4*>(xr + (sbase + 2) * 256 + lane * 4);
        float4 v3 = *reinterpret_cast<const float4*>(xr + (sbase + 3) * 256 + lane * 4);

        // 16 independent compares -> predicate mask
        unsigned m = 0;
#pragma unroll
        for (int j = 0; j < 4; ++j) m |= (f4elem(v0, j) > T_LO ? 1u : 0u) << (0 * 4 + j);
#pragma unroll
        for (int j = 0; j < 4; ++j) m |= (f4elem(v1, j) > T_LO ? 1u : 0u) << (1 * 4 + j);
#pragma unroll
        for (int j = 0; j < 4; ++j) m |= (f4elem(v2, j) > T_LO ? 1u : 0u) << (2 * 4 + j);
#pragma unroll
        for (int j = 0; j < 4; ++j) m |= (f4elem(v3, j) > T_LO ? 1u : 0u) << (3 * 4 + j);
        const unsigned hcnt = __popc(m);   // [0,16] -> 5 bits

        // bit-plane ballot scan (5 independent ballots): lane base + half total
        unsigned base = 0, Ch = 0;
#pragma unroll
        for (int b = 0; b < 5; ++b) {
            ull bal = __ballot(((hcnt >> b) & 1u) != 0u);
            base += ((unsigned)__popcll(bal & lm_lt)) << b;
            Ch   += ((unsigned)__popcll(bal)) << b;
        }

        // branchless LDS compaction of this half's 16 elements
        unsigned pos = C + base;
        const unsigned trash = CAP + (unsigned)lane;
#pragma unroll
        for (int s = 0; s < 4; ++s) {
            const float4 q = (s == 0) ? v0 : (s == 1) ? v1 : (s == 2) ? v2 : v3;
#pragma unroll
            for (int j = 0; j < 4; ++j) {
                unsigned pred = (m >> (s * 4 + j)) & 1u;
                unsigned dst = pred ? pos : trash;
                dst = min(dst, (unsigned)(CAP + 63));
                my[dst] = make_float2(f4elem(q, j),
                    __uint_as_float((unsigned)((sbase + s) * 256 + lane * 4 + j)));
                pos += pred;
            }
        }
        C += Ch;
    }

    if (C >= K_SEL && C <= CAP) {
        // ---- primary: early-exit bitwise radix select, 2 slots/lane ----
        float2 cd0 = my[lane];
        float2 cd1 = my[64 + lane];
        const bool ok0 = (unsigned)lane < C;
        const bool ok1 = (unsigned)(64 + lane) < C;
        const float    cv0 = ok0 ? cd0.x : 0.0f;
        const float    cv1 = ok1 ? cd1.x : 0.0f;
        const unsigned kb0 = __float_as_uint(cv0);  // >1.74 => positive => raw-bit order
        const unsigned kb1 = __float_as_uint(cv1);
        const unsigned cc0 = __float_as_uint(cd0.y);
        const unsigned cc1 = __float_as_uint(cd1.y);

        ull a0 = (C >= 64) ? ~0ull : ((1ull << C) - 1ull);
        ull a1 = (C <= 64) ? 0ull : ((C >= 128) ? ~0ull : ((1ull << (C - 64)) - 1ull));
        ull s0 = 0, s1 = 0;
        unsigned kk = K_SEL, na = C;

        if (na == kk) { s0 = a0; s1 = a1; kk = 0; }
        for (int b = 30; b >= 0 && kk; --b) {
            unsigned bit = 1u << b;
            ull b0 = __ballot((kb0 & bit) != 0) & a0;
            ull b1 = __ballot((kb1 & bit) != 0) & a1;
            unsigned cv = (unsigned)__popcll(b0) + (unsigned)__popcll(b1);
            if (cv >= kk) { a0 = b0; a1 = b1; na = cv; }
            else          { s0 |= b0; s1 |= b1; kk -= cv; a0 &= ~b0; a1 &= ~b1; na -= cv; }
            if (na == kk) { s0 |= a0; s1 |= a1; kk = 0; }
        }
        if (kk) {
            // bits exhausted: alive are exactly-equal values; take kk smallest cols
            ull e0 = a0, e1 = a1;
            for (unsigned t = 0; t < kk; ++t) {
                unsigned mymin = 0xFFFFFFFFu;
                if ((e0 >> lane) & 1ull) mymin = min(mymin, cc0);
                if ((e1 >> lane) & 1ull) mymin = min(mymin, cc1);
#pragma unroll
                for (int off = 32; off >= 1; off >>= 1)
                    mymin = min(mymin, (unsigned)__shfl_xor((int)mymin, off, 64));
                bool h0 = ((e0 >> lane) & 1ull) && cc0 == mymin;
                bool h1 = ((e1 >> lane) & 1ull) && cc1 == mymin;
                ull hb0 = __ballot(h0) & e0;
                ull hb1 = __ballot(h1) & e1;
                if (hb0) { s0 |= hb0 & (~hb0 + 1); e0 &= ~(hb0 & (~hb0 + 1)); }
                else     { s1 |= hb1 & (~hb1 + 1); e1 &= ~(hb1 & (~hb1 + 1)); }
            }
        }

        // ---- emit 40 pairs + column counts (XCD-local histogram copy) ----
        unsigned n0 = (unsigned)__popcll(s0);
        if ((s0 >> lane) & 1ull) {
            unsigned p = (unsigned)__popcll(s0 & lm_lt);
            reinterpret_cast<float2*>(hdr)[p] = make_float2(cv0, __uint_as_float(cc0));
            atomicAdd(&mycnt_arr[cc0], 1u);
        }
        if ((s1 >> lane) & 1ull) {
            unsigned p = n0 + (unsigned)__popcll(s1 & lm_lt);
            reinterpret_cast<float2*>(hdr)[p] = make_float2(cv1, __uint_as_float(cc1));
            atomicAdd(&mycnt_arr[cc1], 1u);
        }
    } else {
        // ---- fully general fallback (statistically never for N(0,1) data):
        //      K exact wave-argmax rounds, reloading from global (L2-hot)
        unsigned rm = 0;
        for (int t = 0; t < K_SEL; ++t) {
            ull best = 0;
#pragma unroll
            for (int s = 0; s < 8; ++s) {
                float4 q = *reinterpret_cast<const float4*>(xr + s * 256 + lane * 4);
#pragma unroll
                for (int j = 0; j < 4; ++j) {
                    int slot = s * 4 + j;
                    if (!((rm >> slot) & 1u)) {
                        ull key = fkey(f4elem(q, j), (unsigned)(s * 256 + lane * 4 + j));
                        best = best > key ? best : key;
                    }
                }
            }
#pragma unroll
            for (int off = 32; off >= 1; off >>= 1) {
                ull o = __shfl_xor(best, off, 64);
                best = best > o ? best : o;
            }
#pragma unroll
            for (int s = 0; s < 8; ++s) {
                float4 q = *reinterpret_cast<const float4*>(xr + s * 256 + lane * 4);
#pragma unroll
                for (int j = 0; j < 4; ++j) {
                    int slot = s * 4 + j;
                    unsigned col = (unsigned)(s * 256 + lane * 4 + j);
                    if (!((rm >> slot) & 1u) && fkey(f4elem(q, j), col) == best) {
                        rm |= 1u << slot;
                        reinterpret_cast<float2*>(hdr)[t] =
                            make_float2(f4elem(q, j), __uint_as_float(col));
                        atomicAdd(&mycnt_arr[col], 1u);
                    }
                }
            }
        }
    }
}

// Kernel 2: sum 16 histogram copies; boost[d] = exp(-(duty*0.99 + 0.01*cnt/B
// - target)). 16 blocks x 128 threads: readers spread over all XCDs.
__global__ __launch_bounds__(128) void kwta_boost_kernel(
        const float* __restrict__ duty, const unsigned* __restrict__ cnt,
        float* __restrict__ boost) {
    int d = blockIdx.x * 128 + threadIdx.x;
    unsigned s = 0;
#pragma unroll
    for (int g = 0; g < G_COPIES; ++g) s += cnt[((size_t)g << 11) + d];
    float mean = (float)s * (1.0f / 32768.0f);
    float nd = duty[d] * (1.0f - ALPHA_F) + ALPHA_F * mean;
    boost[d] = expf(-(nd - TARGET_F));
}

// Kernel 3: block-per-row; read 40 pairs from row header, build row in LDS,
// write fully-coalesced float4s (overwrites header with the real output).
__global__ __launch_bounds__(256) void kwta_scatter_kernel(
        float* __restrict__ out, const float* __restrict__ boost) {
    __shared__ float buf[D_COLS];
    const int t = threadIdx.x;
    const size_t rb = (size_t)blockIdx.x * D_COLS;

    float2 pr = make_float2(0.0f, 0.0f);
    if (t < K_SEL) pr = reinterpret_cast<const float2*>(out + rb)[t];

    float4 z = make_float4(0.0f, 0.0f, 0.0f, 0.0f);
    reinterpret_cast<float4*>(buf)[t * 2]     = z;
    reinterpret_cast<float4*>(buf)[t * 2 + 1] = z;
    __syncthreads();

    if (t < K_SEL) {
        unsigned col = __float_as_uint(pr.y);
        buf[col] = pr.x * boost[col];
    }
    __syncthreads();

    reinterpret_cast<float4*>(out + rb)[t * 2]     = reinterpret_cast<const float4*>(buf)[t * 2];
    reinterpret_cast<float4*>(out + rb)[t * 2 + 1] = reinterpret_cast<const float4*>(buf)[t * 2 + 1];
}

extern "C" void kernel_launch(void* const* d_in, const int* in_sizes, int n_in,
                              void* d_out, int out_size, void* d_ws, size_t ws_size,
                              hipStream_t stream) {
    const float* x    = (const float*)d_in[0];
    const float* duty = (const float*)d_in[1];
    float* out = (float*)d_out;

    unsigned* cnt   = (unsigned*)d_ws;                                 // 16 * 8 KB
    float*    boost = (float*)((char*)d_ws + (size_t)G_COPIES * 8192); // 8 KB

    // zero 16*8KB = 128KB of histograms: 32 blocks x 256 threads x 16B
    kwta_zero_kernel<<<G_COPIES * 8192 / 4096, 256, 0, stream>>>((uint4*)d_ws);

    kwta_topk_kernel<<<B_ROWS / 4, 256, 0, stream>>>(x, out, cnt);
    kwta_boost_kernel<<<D_COLS / 128, 128, 0, stream>>>(duty, cnt, boost);
    kwta_scatter_kernel<<<B_ROWS, 256, 0, stream>>>(out, boost);
}

// Round 10
// 148.912 us; speedup vs baseline: 1.8707x; 1.0385x over previous
//
#include <hip/hip_runtime.h>
#include <hip/hip_bf16.h>

typedef unsigned long long ull;

#define B_ROWS 32768
#define D_COLS 2048
#define K_SEL  40
#define T_LO   1.74f          // P(x>1.74)=0.0409 -> C ~ 84 +- 9, in [40,128] at ~4.9 sigma
#define CAP    128            // 2 select-slots per lane
#define ALPHA_F  0.01f
#define TARGET_F 0.01953125f  // 40/2048 exact
#define G_COPIES 16           // histogram copies; multiple of 8 => XCD-local atomics

__device__ __forceinline__ ull fkey(float vv, unsigned col) {
    // monotone (value desc via max, index asc via ~col) 64-bit key
    unsigned bits = __float_as_uint(vv);
    unsigned sk = (bits & 0x80000000u) ? ~bits : (bits | 0x80000000u);
    return ((ull)sk << 32) | (ull)(unsigned)(~col);
}

__device__ __forceinline__ float f4elem(const float4& q, int j) {
    return j == 0 ? q.x : j == 1 ? q.y : j == 2 ? q.z : q.w;
}

// Kernel 0: zero the privatized histograms (rocclr fillBuffer launches a tiny
// grid for small buffers; DIY at full BW).
__global__ __launch_bounds__(256) void kwta_zero_kernel(uint4* __restrict__ p) {
    p[blockIdx.x * 256 + threadIdx.x] = make_uint4(0u, 0u, 0u, 0u);
}

// Kernel 1: per-row exact top-K, one WAVE per row (R9 two-half structure).
// FUSED=true: wave zero-writes its ENTIRE output row up front (8 float4
// stores with no data dependency — the write stream overlaps load latency),
// emits the 40 (val,col) pairs to a compact ws buffer; the fixup kernel later
// overwrites just the 40 selected slots with val*boost. This deletes the
// 256MB-rewrite scatter pass. FUSED=false: legacy path (pairs to row header,
// scatter pass rebuilds rows) for small ws_size.
template <bool FUSED>
__global__ __launch_bounds__(256) void kwta_topk_kernel(
        const float* __restrict__ x, float* __restrict__ out,
        unsigned* __restrict__ cnt, float2* __restrict__ pairs) {
    __shared__ float2 cands[4][CAP + 64];   // +64 per-lane trash slots

    const int lane = threadIdx.x & 63;
    const int wid  = threadIdx.x >> 6;
    const int row  = blockIdx.x * 4 + wid;
    const float* xr = x + (size_t)row * D_COLS;
    float* orow = out + (size_t)row * D_COLS;
    const ull lm_lt = (1ull << lane) - 1ull;
    float2* my = cands[wid];
    unsigned* mycnt_arr = cnt + ((size_t)(blockIdx.x & (G_COPIES - 1)) << 11);
    float2* prow = FUSED ? (pairs + (size_t)row * K_SEL)
                         : reinterpret_cast<float2*>(orow);

    if (FUSED) {
        // Unconditional full-row zero: no dependencies, issues before the
        // loads so the store stream flows while loads are in flight.
        const float4 z = make_float4(0.0f, 0.0f, 0.0f, 0.0f);
#pragma unroll
        for (int s = 0; s < 8; ++s)
            reinterpret_cast<float4*>(orow + s * 256)[lane] = z;
    }

    unsigned C = 0;   // running candidate count

    // ---- two halves of 16 elements/lane each (keeps VGPR low) ----
#pragma unroll
    for (int h = 0; h < 2; ++h) {
        const int sbase = h * 4;
        float4 v0 = *reinterpret_cast<const float4*>(xr + (sbase + 0) * 256 + lane * 4);
        float4 v1 = *reinterpret_cast<const float4*>(xr + (sbase + 1) * 256 + lane * 4);
        float4 v2 = *reinterpret_cast<const float4*>(xr + (sbase + 2) * 256 + lane * 4);
        float4 v3 = *reinterpret_cast<const float4*>(xr + (sbase + 3) * 256 + lane * 4);

        unsigned m = 0;
#pragma unroll
        for (int j = 0; j < 4; ++j) m |= (f4elem(v0, j) > T_LO ? 1u : 0u) << (0 * 4 + j);
#pragma unroll
        for (int j = 0; j < 4; ++j) m |= (f4elem(v1, j) > T_LO ? 1u : 0u) << (1 * 4 + j);
#pragma unroll
        for (int j = 0; j < 4; ++j) m |= (f4elem(v2, j) > T_LO ? 1u : 0u) << (2 * 4 + j);
#pragma unroll
        for (int j = 0; j < 4; ++j) m |= (f4elem(v3, j) > T_LO ? 1u : 0u) << (3 * 4 + j);
        const unsigned hcnt = __popc(m);   // [0,16] -> 5 bits

        // bit-plane ballot scan (5 independent ballots)
        unsigned base = 0, Ch = 0;
#pragma unroll
        for (int b = 0; b < 5; ++b) {
            ull bal = __ballot(((hcnt >> b) & 1u) != 0u);
            base += ((unsigned)__popcll(bal & lm_lt)) << b;
            Ch   += ((unsigned)__popcll(bal)) << b;
        }

        // branchless LDS compaction
        unsigned pos = C + base;
        const unsigned trash = CAP + (unsigned)lane;
#pragma unroll
        for (int s = 0; s < 4; ++s) {
            const float4 q = (s == 0) ? v0 : (s == 1) ? v1 : (s == 2) ? v2 : v3;
#pragma unroll
            for (int j = 0; j < 4; ++j) {
                unsigned pred = (m >> (s * 4 + j)) & 1u;
                unsigned dst = pred ? pos : trash;
                dst = min(dst, (unsigned)(CAP + 63));
                my[dst] = make_float2(f4elem(q, j),
                    __uint_as_float((unsigned)((sbase + s) * 256 + lane * 4 + j)));
                pos += pred;
            }
        }
        C += Ch;
    }

    if (C >= K_SEL && C <= CAP) {
        // ---- primary: early-exit bitwise radix select, 2 slots/lane ----
        float2 cd0 = my[lane];
        float2 cd1 = my[64 + lane];
        const bool ok0 = (unsigned)lane < C;
        const bool ok1 = (unsigned)(64 + lane) < C;
        const float    cv0 = ok0 ? cd0.x : 0.0f;
        const float    cv1 = ok1 ? cd1.x : 0.0f;
        const unsigned kb0 = __float_as_uint(cv0);  // >1.74 => positive => raw-bit order
        const unsigned kb1 = __float_as_uint(cv1);
        const unsigned cc0 = __float_as_uint(cd0.y);
        const unsigned cc1 = __float_as_uint(cd1.y);

        ull a0 = (C >= 64) ? ~0ull : ((1ull << C) - 1ull);
        ull a1 = (C <= 64) ? 0ull : ((C >= 128) ? ~0ull : ((1ull << (C - 64)) - 1ull));
        ull s0 = 0, s1 = 0;
        unsigned kk = K_SEL, na = C;

        if (na == kk) { s0 = a0; s1 = a1; kk = 0; }
        for (int b = 30; b >= 0 && kk; --b) {
            unsigned bit = 1u << b;
            ull b0 = __ballot((kb0 & bit) != 0) & a0;
            ull b1 = __ballot((kb1 & bit) != 0) & a1;
            unsigned cv = (unsigned)__popcll(b0) + (unsigned)__popcll(b1);
            if (cv >= kk) { a0 = b0; a1 = b1; na = cv; }
            else          { s0 |= b0; s1 |= b1; kk -= cv; a0 &= ~b0; a1 &= ~b1; na -= cv; }
            if (na == kk) { s0 |= a0; s1 |= a1; kk = 0; }
        }
        if (kk) {
            // bits exhausted: alive are exactly-equal values; take kk smallest cols
            ull e0 = a0, e1 = a1;
            for (unsigned t = 0; t < kk; ++t) {
                unsigned mymin = 0xFFFFFFFFu;
                if ((e0 >> lane) & 1ull) mymin = min(mymin, cc0);
                if ((e1 >> lane) & 1ull) mymin = min(mymin, cc1);
#pragma unroll
                for (int off = 32; off >= 1; off >>= 1)
                    mymin = min(mymin, (unsigned)__shfl_xor((int)mymin, off, 64));
                bool h0 = ((e0 >> lane) & 1ull) && cc0 == mymin;
                bool h1 = ((e1 >> lane) & 1ull) && cc1 == mymin;
                ull hb0 = __ballot(h0) & e0;
                ull hb1 = __ballot(h1) & e1;
                if (hb0) { s0 |= hb0 & (~hb0 + 1); e0 &= ~(hb0 & (~hb0 + 1)); }
                else     { s1 |= hb1 & (~hb1 + 1); e1 &= ~(hb1 & (~hb1 + 1)); }
            }
        }

        // ---- emit 40 pairs + column counts (XCD-local histogram copy) ----
        unsigned n0 = (unsigned)__popcll(s0);
        if ((s0 >> lane) & 1ull) {
            unsigned p = (unsigned)__popcll(s0 & lm_lt);
            prow[p] = make_float2(cv0, __uint_as_float(cc0));
            atomicAdd(&mycnt_arr[cc0], 1u);
        }
        if ((s1 >> lane) & 1ull) {
            unsigned p = n0 + (unsigned)__popcll(s1 & lm_lt);
            prow[p] = make_float2(cv1, __uint_as_float(cc1));
            atomicAdd(&mycnt_arr[cc1], 1u);
        }
    } else {
        // ---- fully general fallback (statistically never for N(0,1) data):
        //      K exact wave-argmax rounds, reloading from global (L2-hot)
        unsigned rm = 0;
        for (int t = 0; t < K_SEL; ++t) {
            ull best = 0;
#pragma unroll
            for (int s = 0; s < 8; ++s) {
                float4 q = *reinterpret_cast<const float4*>(xr + s * 256 + lane * 4);
#pragma unroll
                for (int j = 0; j < 4; ++j) {
                    int slot = s * 4 + j;
                    if (!((rm >> slot) & 1u)) {
                        ull key = fkey(f4elem(q, j), (unsigned)(s * 256 + lane * 4 + j));
                        best = best > key ? best : key;
                    }
                }
            }
#pragma unroll
            for (int off = 32; off >= 1; off >>= 1) {
                ull o = __shfl_xor(best, off, 64);
                best = best > o ? best : o;
            }
#pragma unroll
            for (int s = 0; s < 8; ++s) {
                float4 q = *reinterpret_cast<const float4*>(xr + s * 256 + lane * 4);
#pragma unroll
                for (int j = 0; j < 4; ++j) {
                    int slot = s * 4 + j;
                    unsigned col = (unsigned)(s * 256 + lane * 4 + j);
                    if (!((rm >> slot) & 1u) && fkey(f4elem(q, j), col) == best) {
                        rm |= 1u << slot;
                        prow[t] = make_float2(f4elem(q, j), __uint_as_float(col));
                        atomicAdd(&mycnt_arr[col], 1u);
                    }
                }
            }
        }
    }
}

// Kernel 2: sum 16 histogram copies; boost[d] = exp(-(duty*0.99 + 0.01*cnt/B
// - target)). 16 blocks x 128 threads: readers spread over all XCDs.
__global__ __launch_bounds__(128) void kwta_boost_kernel(
        const float* __restrict__ duty, const unsigned* __restrict__ cnt,
        float* __restrict__ boost) {
    int d = blockIdx.x * 128 + threadIdx.x;
    unsigned s = 0;
#pragma unroll
    for (int g = 0; g < G_COPIES; ++g) s += cnt[((size_t)g << 11) + d];
    float mean = (float)s * (1.0f / 32768.0f);
    float nd = duty[d] * (1.0f - ALPHA_F) + ALPHA_F * mean;
    boost[d] = expf(-(nd - TARGET_F));
}

// Kernel 3 (fused path): one thread per (row,k) pair — overwrite the selected
// slot with val*boost[col]. ~10.5MB coalesced pair reads + 1.31M scattered
// 4B stores; boost (8KB) is cache-hot.
__global__ __launch_bounds__(256) void kwta_fixup_kernel(
        float* __restrict__ out, const float2* __restrict__ pairs,
        const float* __restrict__ boost) {
    const int gid = blockIdx.x * 256 + threadIdx.x;
    const float2 pr = pairs[gid];
    const unsigned col = __float_as_uint(pr.y);
    const int row = gid / K_SEL;
    out[(size_t)row * D_COLS + col] = pr.x * boost[col];
}

// Kernel 3 (legacy path): block-per-row scatter via LDS (used only if ws_size
// can't hold the pairs buffer).
__global__ __launch_bounds__(256) void kwta_scatter_kernel(
        float* __restrict__ out, const float* __restrict__ boost) {
    __shared__ float buf[D_COLS];
    const int t = threadIdx.x;
    const size_t rb = (size_t)blockIdx.x * D_COLS;

    float2 pr = make_float2(0.0f, 0.0f);
    if (t < K_SEL) pr = reinterpret_cast<const float2*>(out + rb)[t];

    float4 z = make_float4(0.0f, 0.0f, 0.0f, 0.0f);
    reinterpret_cast<float4*>(buf)[t * 2]     = z;
    reinterpret_cast<float4*>(buf)[t * 2 + 1] = z;
    __syncthreads();

    if (t < K_SEL) {
        unsigned col = __float_as_uint(pr.y);
        buf[col] = pr.x * boost[col];
    }
    __syncthreads();

    reinterpret_cast<float4*>(out + rb)[t * 2]     = reinterpret_cast<const float4*>(buf)[t * 2];
    reinterpret_cast<float4*>(out + rb)[t * 2 + 1] = reinterpret_cast<const float4*>(buf)[t * 2 + 1];
}

extern "C" void kernel_launch(void* const* d_in, const int* in_sizes, int n_in,
                              void* d_out, int out_size, void* d_ws, size_t ws_size,
                              hipStream_t stream) {
    const float* x    = (const float*)d_in[0];
    const float* duty = (const float*)d_in[1];
    float* out = (float*)d_out;

    const size_t CNT_BYTES   = (size_t)G_COPIES * 8192;          // 128 KB
    const size_t PAIRS_BYTES = (size_t)B_ROWS * K_SEL * 8;       // 10.49 MB

    unsigned* cnt   = (unsigned*)d_ws;
    float*    boost = (float*)((char*)d_ws + CNT_BYTES);
    float2*   pairs = (float2*)((char*)d_ws + CNT_BYTES + 8192);

    const bool fused = ws_size >= CNT_BYTES + 8192 + PAIRS_BYTES;

    // zero the 128KB of histograms
    kwta_zero_kernel<<<CNT_BYTES / 4096, 256, 0, stream>>>((uint4*)d_ws);

    if (fused) {
        kwta_topk_kernel<true><<<B_ROWS / 4, 256, 0, stream>>>(x, out, cnt, pairs);
        kwta_boost_kernel<<<D_COLS / 128, 128, 0, stream>>>(duty, cnt, boost);
        kwta_fixup_kernel<<<B_ROWS * K_SEL / 256, 256, 0, stream>>>(out, pairs, boost);
    } else {
        kwta_topk_kernel<false><<<B_ROWS / 4, 256, 0, stream>>>(x, out, cnt, nullptr);
        kwta_boost_kernel<<<D_COLS / 128, 128, 0, stream>>>(duty, cnt, boost);
        kwta_scatter_kernel<<<B_ROWS, 256, 0, stream>>>(out, boost);
    }
}